// Round 12
// baseline (1342.503 us; speedup 1.0000x reference)
//
#include <hip/hip_runtime.h>

#define PIX 25088
#define NB 8
#define HH 56
#define WW 56
#define CC 256
#define P2 49
#define TOPKN 4

typedef short s16x8 __attribute__((ext_vector_type(8)));
typedef float f32x4 __attribute__((ext_vector_type(4)));

__device__ __forceinline__ float gelu_f(float v){
    return 0.5f*v*(1.0f+erff(v*0.70710678118654752f));
}
__device__ __forceinline__ float sigmoid_f(float v){
    return 1.0f/(1.0f+__expf(-v));
}
__device__ __forceinline__ unsigned short f2bf(float f){
    union { float f; unsigned u; } x; x.f = f;
    unsigned r = x.u + 0x7fffu + ((x.u >> 16) & 1u);
    return (unsigned short)(r >> 16);
}
__device__ __forceinline__ float bf2f(unsigned short u){
    union { unsigned u; float f; } x; x.u = ((unsigned)u) << 16; return x.f;
}
__device__ __forceinline__ void gload_lds16(const void* g, void* l){
    __builtin_amdgcn_global_load_lds((const __attribute__((address_space(1))) void*)g,
                                     (__attribute__((address_space(3))) void*)l, 16, 0, 0);
}

// ---------------- NCHW -> NHWC transpose (tiled, f32) ----------------
__global__ __launch_bounds__(1024) void nchw_to_nhwc(const float* __restrict__ in, float* __restrict__ out){
    __shared__ float t[32][33];
    int pb = blockIdx.x;            // n * 98 + p-tile
    int n  = pb / 98;
    int p0 = (pb % 98) * 32;
    int c0 = blockIdx.y * 32;
    int tx = threadIdx.x, ty = threadIdx.y;
    t[ty][tx] = in[(size_t)(n*CC + c0+ty)*3136 + p0 + tx];
    __syncthreads();
    out[(size_t)(n*3136 + p0 + ty)*CC + c0 + tx] = t[tx][ty];
}

// ---------------- weight transpose+convert: f32 [K,N] (xLAYERS) -> bf16 [N,K] ----------------
__global__ __launch_bounds__(1024) void wtrans(const float* __restrict__ in, unsigned short* __restrict__ out,
                                               int K, int N){
    int layer = blockIdx.z;
    in  += (size_t)layer*K*N;
    out += (size_t)layer*K*N;
    __shared__ float t[32][33];
    int n0 = blockIdx.x*32, k0 = blockIdx.y*32;
    t[threadIdx.y][threadIdx.x] = in[(size_t)(k0+threadIdx.y)*N + n0 + threadIdx.x];
    __syncthreads();
    out[(size_t)(n0+threadIdx.y)*K + k0 + threadIdx.x] = f2bf(t[threadIdx.x][threadIdx.y]);
}

// ---------------- elementwise f32 -> bf16 ----------------
__global__ __launch_bounds__(256) void tobf16(const float* __restrict__ in, unsigned short* __restrict__ out, int n){
    int i = blockIdx.x*256 + threadIdx.x;
    if(i < n) out[i] = f2bf(in[i]);
}

// ---------------- conv weight reorder: [o][c][3][3] f32 -> [tap][o][c] bf16 ----------------
__global__ __launch_bounds__(256) void convw_reorder(const float* __restrict__ in, unsigned short* __restrict__ out){
    int idx = blockIdx.x*256 + threadIdx.x;      // over 256*256*9
    if(idx >= 256*256*9) return;
    int o = idx / (256*9); int rem = idx % (256*9); int c = rem/9; int t = rem%9;
    out[(size_t)t*65536 + o*256 + c] = f2bf(in[idx]);
}

// ---------------- LayerNorm over C=256, wave per row, bf16 out ----------------
__global__ __launch_bounds__(256) void ln_bf16(const float* __restrict__ x, const float* __restrict__ w,
                                               const float* __restrict__ b, unsigned short* __restrict__ y){
    int row = blockIdx.x*4 + (threadIdx.x >> 6);
    int lane = threadIdx.x & 63;
    const float4 v = *reinterpret_cast<const float4*>(&x[(size_t)row*CC + lane*4]);
    float s = v.x + v.y + v.z + v.w;
    #pragma unroll
    for(int off=32; off>0; off>>=1) s += __shfl_xor(s, off);
    float mu = s*(1.0f/CC);
    float d0=v.x-mu, d1=v.y-mu, d2=v.z-mu, d3=v.w-mu;
    float sq = d0*d0 + d1*d1 + d2*d2 + d3*d3;
    #pragma unroll
    for(int off=32; off>0; off>>=1) sq += __shfl_xor(sq, off);
    float rs = rsqrtf(sq*(1.0f/CC) + 1e-6f);
    const float4 wv = *reinterpret_cast<const float4*>(&w[lane*4]);
    const float4 bv = *reinterpret_cast<const float4*>(&b[lane*4]);
    ushort4 o;
    o.x = f2bf(d0*rs*wv.x + bv.x);
    o.y = f2bf(d1*rs*wv.y + bv.y);
    o.z = f2bf(d2*rs*wv.z + bv.z);
    o.w = f2bf(d3*rs*wv.w + bv.w);
    *reinterpret_cast<ushort4*>(&y[(size_t)row*CC + lane*4]) = o;
}

// ---------------- MFMA GEMM: A bf16 [M,K], Bt bf16 [N,K], 128x128 tile, BK=64 ----------------
// LDS row = 64 bf16 = 128 B; slot(16B) XOR-swizzled by (row&7) on BOTH store-source and read.
// EPI: 0 none, 1 gelu, 2 sigmoid, 3 fused SSE-gate (Cb = padded bf16 image, needs gfac+res).
// HASRES: add res[M,N] f32 after EPI.  OUTF: write f32 Cf, OUTB: write bf16 Cb.
template<int EPI, bool HASRES, bool OUTF, bool OUTB>
__global__ __launch_bounds__(256) void mfma_gemm(
    const unsigned short* __restrict__ A, const unsigned short* __restrict__ Bt,
    const float* __restrict__ bias, const float* __restrict__ res,
    const float* __restrict__ gfac,
    float* __restrict__ Cf, unsigned short* __restrict__ Cb,
    int M, int N, int K)
{
    __shared__ __align__(16) unsigned short As[8192];
    __shared__ __align__(16) unsigned short Bs[8192];
    const int tid = threadIdx.x;
    const int wid = tid >> 6, lane = tid & 63;
    const int row0 = blockIdx.y << 7, col0 = blockIdx.x << 7;
    const int wm = wid >> 1, wn = wid & 1;
    const int li = lane & 15, qq = lane >> 4;
    const int grow = (wid<<5) + (lane>>3);              // + i*8
    const int gq   = (lane&7) ^ ((lane>>3)&7);          // pre-swizzled global chunk

    f32x4 acc[4][4] = {};
    const int nk = K >> 6;
    for(int kt=0; kt<nk; kt++){
        const int k0 = kt << 6;
        #pragma unroll
        for(int i=0;i<4;i++){
            int r = grow + i*8;
            gload_lds16(A  + (size_t)(row0+r)*K + k0 + gq*8, (char*)As + wid*4096 + i*1024);
            gload_lds16(Bt + (size_t)(col0+r)*K + k0 + gq*8, (char*)Bs + wid*4096 + i*1024);
        }
        __syncthreads();
        #pragma unroll
        for(int ks=0;ks<2;ks++){
            s16x8 af[4], bfr[4];
            #pragma unroll
            for(int mi=0;mi<4;mi++){
                int r = (wm<<6) + (mi<<4) + li;
                int slot = (ks*4+qq) ^ (r&7);
                af[mi] = *(const s16x8*)((const char*)As + r*128 + slot*16);
            }
            #pragma unroll
            for(int nj=0;nj<4;nj++){
                int r = (wn<<6) + (nj<<4) + li;
                int slot = (ks*4+qq) ^ (r&7);
                bfr[nj] = *(const s16x8*)((const char*)Bs + r*128 + slot*16);
            }
            #pragma unroll
            for(int mi=0;mi<4;mi++)
                #pragma unroll
                for(int nj=0;nj<4;nj++)
                    acc[mi][nj] = __builtin_amdgcn_mfma_f32_16x16x32_bf16(af[mi], bfr[nj], acc[mi][nj], 0,0,0);
        }
        __syncthreads();
    }
    #pragma unroll
    for(int mi=0;mi<4;mi++){
        #pragma unroll
        for(int nj=0;nj<4;nj++){
            int col = col0 + (wn<<6) + (nj<<4) + li;
            float bv = bias ? bias[col] : 0.0f;
            #pragma unroll
            for(int rr=0;rr<4;rr++){
                int row = row0 + (wm<<6) + (mi<<4) + (qq<<2) + rr;
                float v = acc[mi][nj][rr] + bv;
                if(EPI==1) v = gelu_f(v);
                if(EPI==2) v = sigmoid_f(v);
                if(EPI==3){
                    int n = row / 3136; int rem = row % 3136;
                    int h = rem / 56, w = rem % 56;
                    float xv = res[(size_t)row*N + col];
                    v = xv*(gfac[n*CC + col] + sigmoid_f(v));
                    size_t dst = ((size_t)(64 + n*3364 + (h+1)*58 + (w+1)))*CC + col;
                    Cb[dst] = f2bf(v);
                } else {
                    if(HASRES) v += res[(size_t)row*N + col];
                    if(OUTF) Cf[(size_t)row*N + col] = v;
                    if(OUTB) Cb[(size_t)row*N + col] = f2bf(v);
                }
            }
        }
    }
}

// ---------------- conv 3x3 as 9-tap accumulated MFMA GEMM over padded image (BK=64) ----------------
__global__ __launch_bounds__(256) void conv_gemm(
    const unsigned short* __restrict__ P, const unsigned short* __restrict__ CBt,
    const float* __restrict__ bias, float* __restrict__ out)
{
    __shared__ __align__(16) unsigned short As[8192];
    __shared__ __align__(16) unsigned short Bs[8192];
    const int tid = threadIdx.x;
    const int wid = tid >> 6, lane = tid & 63;
    const int row0 = blockIdx.y << 7, col0 = blockIdx.x << 7;
    const int wm = wid >> 1, wn = wid & 1;
    const int li = lane & 15, qq = lane >> 4;
    const int grow = (wid<<5) + (lane>>3);
    const int gq   = (lane&7) ^ ((lane>>3)&7);
    const int K = 256;

    f32x4 acc[4][4] = {};
    for(int tap=0; tap<9; tap++){
        int d = ((tap/3)-1)*58 + (tap%3) - 1;
        const unsigned short* A  = P + (size_t)(64 + d)*256;
        const unsigned short* Bt = CBt + (size_t)tap*65536;
        for(int kt=0; kt<4; kt++){
            const int k0 = kt << 6;
            #pragma unroll
            for(int i=0;i<4;i++){
                int r = grow + i*8;
                gload_lds16(A  + (size_t)(row0+r)*K + k0 + gq*8, (char*)As + wid*4096 + i*1024);
                gload_lds16(Bt + (size_t)(col0+r)*K + k0 + gq*8, (char*)Bs + wid*4096 + i*1024);
            }
            __syncthreads();
            #pragma unroll
            for(int ks=0;ks<2;ks++){
                s16x8 af[4], bfr[4];
                #pragma unroll
                for(int mi=0;mi<4;mi++){
                    int r = (wm<<6) + (mi<<4) + li;
                    int slot = (ks*4+qq) ^ (r&7);
                    af[mi] = *(const s16x8*)((const char*)As + r*128 + slot*16);
                }
                #pragma unroll
                for(int nj=0;nj<4;nj++){
                    int r = (wn<<6) + (nj<<4) + li;
                    int slot = (ks*4+qq) ^ (r&7);
                    bfr[nj] = *(const s16x8*)((const char*)Bs + r*128 + slot*16);
                }
                #pragma unroll
                for(int mi=0;mi<4;mi++)
                    #pragma unroll
                    for(int nj=0;nj<4;nj++)
                        acc[mi][nj] = __builtin_amdgcn_mfma_f32_16x16x32_bf16(af[mi], bfr[nj], acc[mi][nj], 0,0,0);
            }
            __syncthreads();
        }
    }
    #pragma unroll
    for(int mi=0;mi<4;mi++){
        #pragma unroll
        for(int nj=0;nj<4;nj++){
            int col = col0 + (wn<<6) + (nj<<4) + li;
            float bv = bias[col];
            #pragma unroll
            for(int rr=0;rr<4;rr++){
                int prow = row0 + (wm<<6) + (mi<<4) + (qq<<2) + rr;
                if(prow < NB*3364){
                    int n = prow / 3364; int rem = prow % 3364;
                    int y = rem / 58, x = rem % 58;
                    if(y>=1 && y<57 && x>=1 && x<57){
                        out[(((size_t)n*CC + col)*HH + (y-1))*WW + (x-1)] = acc[mi][nj][rr] + bv;
                    }
                }
            }
        }
    }
}

// ---------------- region means of q and k (bf16 qkv) ----------------
__global__ __launch_bounds__(256) void winmean_kernel(const unsigned short* __restrict__ qkv,
                                                      float* __restrict__ qwin, float* __restrict__ kwin){
    int b = blockIdx.x;      // n*49 + p
    int n = b / P2, p = b % P2;
    int c = threadIdx.x;
    int hb = (p/7)*8, wb = (p%7)*8;
    float sq=0.f, sk=0.f;
    for(int pixi=0;pixi<64;pixi++){
        int h = hb + (pixi>>3), w = wb + (pixi&7);
        const unsigned short* row = &qkv[((size_t)(n*HH+h)*WW + w)*768];
        sq += bf2f(row[c]);
        sk += bf2f(row[256+c]);
    }
    qwin[(size_t)b*CC+c] = sq*(1.0f/64.0f);
    kwin[(size_t)b*CC+c] = sk*(1.0f/64.0f);
}

// ---------------- routing logits + top-4 ----------------
__global__ __launch_bounds__(64) void route_kernel(const float* __restrict__ qwin, const float* __restrict__ kwin,
                                                   int* __restrict__ idxout){
    int b = blockIdx.x;      // n*49 + p
    int n = b / P2;
    int j = threadIdx.x;
    __shared__ float lg[64];
    float v = -1e30f;
    if(j < P2){
        const float* q = &qwin[(size_t)b*CC];
        const float* k = &kwin[(size_t)(n*P2+j)*CC];
        float s=0.f;
        for(int c=0;c<CC;c++) s += q[c]*k[c];
        v = s*0.0625f;
    }
    lg[j] = v;
    __syncthreads();
    if(j==0){
        for(int t=0;t<TOPKN;t++){
            int best=0; float bv=lg[0];
            for(int u=1;u<P2;u++) if(lg[u]>bv){bv=lg[u];best=u;}
            idxout[b*TOPKN+t]=best;
            lg[best]=-1e30f;
        }
    }
}

// ---------------- MFMA flash attention: ONE WAVE per (n,p,head), bf16 qkv, bf16 out ----------------
__global__ __launch_bounds__(64) void attn_kernel(const unsigned short* __restrict__ qkv,
                                                  const int* __restrict__ idx,
                                                  unsigned short* __restrict__ out){
    __shared__ __align__(16) unsigned short P_lds[64*32];   // [q][key] bf16, byte ^= (q&3)<<4
    __shared__ int pixo[256];                               // gathered global pixel index per key
    int b = blockIdx.x;
    int m = b & 7; int np = b >> 3;      // np = n*49+p
    int n = np / P2, p = np % P2;
    int lane = threadIdx.x;
    int li = lane & 15, g = lane >> 4;
    int hb = (p/7)*8, wb = (p%7)*8;

    #pragma unroll
    for(int t4=0;t4<4;t4++){
        int r = idx[np*TOPKN + t4];           // wave-uniform
        int pixi = lane;
        int h = (r/7)*8 + (pixi>>3), w = (r%7)*8 + (pixi&7);
        pixo[t4*64 + lane] = (n*HH+h)*WW + w;
    }
    __syncthreads();

    // Q fragments (B-operand of S^T): row=q=li+q4*16, k=ch=g*8+j — direct 16B loads
    s16x8 qfr[4];
    #pragma unroll
    for(int q4=0;q4<4;q4++){
        int q = q4*16 + li;
        int h = hb + (q>>3), w = wb + (q&7);
        qfr[q4] = *reinterpret_cast<const s16x8*>(&qkv[((size_t)(n*HH+h)*WW + w)*768 + m*32 + g*8]);
    }

    const float SC = 0.0625f * 1.44269504088896f;
    f32x4 ot[2][4] = {};                 // O^T frags [chf][qf]
    float mx[4], lsum[4];
    #pragma unroll
    for(int q4=0;q4<4;q4++){ mx[q4] = -3e38f; lsum[q4] = 0.0f; }

    for(int kb=0; kb<8; kb++){
        // ---- S^T tile (32 keys x 64 queries) ----
        f32x4 st[2][4] = {};
        #pragma unroll
        for(int kf=0;kf<2;kf++){
            int key = kb*32 + kf*16 + li;
            s16x8 kfrag = *reinterpret_cast<const s16x8*>(&qkv[(size_t)pixo[key]*768 + 256 + m*32 + g*8]);
            #pragma unroll
            for(int q4=0;q4<4;q4++)
                st[kf][q4] = __builtin_amdgcn_mfma_f32_16x16x32_bf16(kfrag, qfr[q4], st[kf][q4], 0,0,0);
        }
        #pragma unroll
        for(int kf=0;kf<2;kf++)
            #pragma unroll
            for(int q4=0;q4<4;q4++)
                #pragma unroll
                for(int r=0;r<4;r++) st[kf][q4][r] *= SC;
        // ---- online softmax per query column (q = li + q4*16) ----
        #pragma unroll
        for(int q4=0;q4<4;q4++){
            float pm = st[0][q4][0];
            #pragma unroll
            for(int r=1;r<4;r++) pm = fmaxf(pm, st[0][q4][r]);
            #pragma unroll
            for(int r=0;r<4;r++) pm = fmaxf(pm, st[1][q4][r]);
            pm = fmaxf(pm, __shfl_xor(pm, 16));
            pm = fmaxf(pm, __shfl_xor(pm, 32));
            float mnew = fmaxf(mx[q4], pm);
            float fsc = exp2f(mx[q4] - mnew);
            mx[q4] = mnew;
            float ps = 0.0f;
            #pragma unroll
            for(int kf=0;kf<2;kf++)
                #pragma unroll
                for(int r=0;r<4;r++){
                    float pv = exp2f(st[kf][q4][r] - mnew);
                    st[kf][q4][r] = pv;
                    ps += pv;
                }
            ps += __shfl_xor(ps, 16);
            ps += __shfl_xor(ps, 32);
            lsum[q4] = lsum[q4]*fsc + ps;
            #pragma unroll
            for(int chf=0;chf<2;chf++)
                #pragma unroll
                for(int r=0;r<4;r++) ot[chf][q4][r] *= fsc;
        }
        // ---- write P^T to LDS ----
        #pragma unroll
        for(int q4=0;q4<4;q4++){
            int q = q4*16 + li;
            #pragma unroll
            for(int kf=0;kf<2;kf++){
                unsigned lo = ((unsigned)f2bf(st[kf][q4][0])) | (((unsigned)f2bf(st[kf][q4][1]))<<16);
                unsigned hi = ((unsigned)f2bf(st[kf][q4][2])) | (((unsigned)f2bf(st[kf][q4][3]))<<16);
                int byte = (q*64 + kf*32 + g*8) ^ ((q&3)<<4);
                *reinterpret_cast<uint2*>((char*)P_lds + byte) = make_uint2(lo, hi);
            }
        }
        __syncthreads();
        // ---- read P^T back as B-frags ----
        s16x8 pfr[4];
        #pragma unroll
        for(int q4=0;q4<4;q4++){
            int q = q4*16 + li;
            int byte = (q*64 + g*16) ^ ((q&3)<<4);
            pfr[q4] = *reinterpret_cast<const s16x8*>((const char*)P_lds + byte);
        }
        // ---- O^T += V^T * P^T ----
        #pragma unroll
        for(int chf=0;chf<2;chf++){
            s16x8 vfr;
            #pragma unroll
            for(int j=0;j<8;j++){
                int key = kb*32 + g*8 + j;
                vfr[j] = (short)qkv[(size_t)pixo[key]*768 + 512 + m*32 + chf*16 + li];
            }
            #pragma unroll
            for(int q4=0;q4<4;q4++)
                ot[chf][q4] = __builtin_amdgcn_mfma_f32_16x16x32_bf16(vfr, pfr[q4], ot[chf][q4], 0,0,0);
        }
        __syncthreads();
    }
    // ---- epilogue (bf16 out) ----
    #pragma unroll
    for(int q4=0;q4<4;q4++){
        int q = q4*16 + li;
        int h = hb + (q>>3), w = wb + (q&7);
        float inv = 1.0f / lsum[q4];
        unsigned short* orow = &out[((size_t)(n*HH+h)*WW + w)*CC + m*32];
        #pragma unroll
        for(int chf=0;chf<2;chf++)
            #pragma unroll
            for(int r=0;r<4;r++)
                orow[chf*16 + g*4 + r] = f2bf(ot[chf][q4][r]*inv);
    }
}

// ---------------- LEPE tiled: attn_out(bf16) + dwconv5(v bf16) -> bf16 ----------------
__global__ __launch_bounds__(256) void lepe_kernel(const unsigned short* __restrict__ qkv,
                                                   const unsigned short* __restrict__ attn,
                                                   const float* __restrict__ lw, const float* __restrict__ lb,
                                                   unsigned short* __restrict__ outb){
    __shared__ float tile[144][64];     // 12x12 spatial halo x 64 channels
    int tileid = blockIdx.x;            // 0..48
    int cg = blockIdx.y;                // 0..3
    int n = blockIdx.z;
    int hb = (tileid/7)*8, wb = (tileid%7)*8;
    int tid = threadIdx.x;
    for(int ii=tid; ii<144*64; ii+=256){
        int sp = ii >> 6, cl = ii & 63;
        int ty = sp / 12, tx = sp % 12;
        int y = hb + ty - 2, x = wb + tx - 2;
        float v = 0.0f;
        if(y>=0 && y<HH && x>=0 && x<WW)
            v = bf2f(qkv[((size_t)(n*HH+y)*WW + x)*768 + 512 + cg*64 + cl]);
        tile[sp][cl] = v;
    }
    __syncthreads();
    int cl = tid & 63;
    int c = cg*64 + cl;
    float wv[25];
    #pragma unroll
    for(int t=0;t<25;t++) wv[t] = lw[c*25 + t];
    float bias = lb[c];
    for(int oi = tid; oi < 4096; oi += 256){
        int sp = oi >> 6;
        int py = sp >> 3, px = sp & 7;
        float a = bias;
        #pragma unroll
        for(int dy=0;dy<5;dy++)
            #pragma unroll
            for(int dx=0;dx<5;dx++)
                a += tile[(py+dy)*12 + px+dx][cl]*wv[dy*5+dx];
        size_t pix = (size_t)(n*HH + hb+py)*WW + wb+px;
        outb[pix*CC + c] = f2bf(bf2f(attn[pix*CC + c]) + a);
    }
}

// ---------------- global average pool: 392 blocks, atomic accumulate of mean ----------------
__global__ __launch_bounds__(256) void pool_kernel(const float* __restrict__ x, float* __restrict__ pooled){
    int n = blockIdx.y, c = threadIdx.x;
    int p0 = blockIdx.x*64;
    float s=0.f;
    for(int pp=0;pp<64;pp++) s += x[((size_t)n*3136 + p0 + pp)*CC + c];
    atomicAdd(&pooled[n*CC+c], s*(1.0f/3136.0f));
}

// ---------------- channel SE (two tiny FCs) ----------------
__global__ __launch_bounds__(256) void cse_kernel(const float* __restrict__ pooled,
                                                  const float* __restrict__ w1, const float* __restrict__ b1,
                                                  const float* __restrict__ w2, const float* __restrict__ b2,
                                                  float* __restrict__ cfac){
    int n = blockIdx.x, t = threadIdx.x;
    __shared__ float c1[16];
    if(t < 16){
        float s = b1[t];
        for(int c=0;c<CC;c++) s += pooled[n*CC+c]*w1[t*CC+c];
        c1[t] = fmaxf(s, 0.0f);
    }
    __syncthreads();
    float s = b2[t];
    #pragma unroll
    for(int j=0;j<16;j++) s += c1[j]*w2[t*16+j];
    cfac[n*CC+t] = sigmoid_f(s);
}

extern "C" void kernel_launch(void* const* d_in, const int* in_sizes, int n_in,
                              void* d_out, int out_size, void* d_ws, size_t ws_size,
                              hipStream_t stream){
    const float* x_in   = (const float*)d_in[0];
    const float* ln1w   = (const float*)d_in[1];
    const float* ln1b   = (const float*)d_in[2];
    const float* qkvw   = (const float*)d_in[3];
    const float* qkvb   = (const float*)d_in[4];
    const float* lepew  = (const float*)d_in[5];
    const float* lepeb  = (const float*)d_in[6];
    const float* wow    = (const float*)d_in[7];
    const float* wob    = (const float*)d_in[8];
    const float* ln2w   = (const float*)d_in[9];
    const float* ln2b   = (const float*)d_in[10];
    const float* mlp1w  = (const float*)d_in[11];
    const float* mlp1b  = (const float*)d_in[12];
    const float* mlp2w  = (const float*)d_in[13];
    const float* mlp2b  = (const float*)d_in[14];
    const float* cse1w  = (const float*)d_in[15];
    const float* cse1b  = (const float*)d_in[16];
    const float* cse2w  = (const float*)d_in[17];
    const float* cse2b  = (const float*)d_in[18];
    const float* ssew   = (const float*)d_in[19];
    const float* sseb   = (const float*)d_in[20];
    const float* convw  = (const float*)d_in[21];
    const float* convb  = (const float*)d_in[22];
    float* out = (float*)d_out;

    char* base = (char*)d_ws;
    float* bufx   = (float*)base;                         base += (size_t)PIX*CC*4;
    float* buftmp = (float*)base;                         base += (size_t)PIX*CC*4;
    // big region: holds qkv bf16 [PIX,768] OR hid bf16 [PIX,1024] OR Ppad [27136,256] bf16
    unsigned short* qkvB = (unsigned short*)base;
    unsigned short* hid  = (unsigned short*)base;
    unsigned short* Ppad = (unsigned short*)base;         base += (size_t)PIX*1024*2;
    float* qwin   = (float*)base;                         base += (size_t)NB*P2*CC*4;
    float* kwin   = (float*)base;                         base += (size_t)NB*P2*CC*4;
    float* pooled = (float*)base;                         base += NB*CC*4;
    float* cfac   = (float*)base;                         base += NB*CC*4;
    int*   idxb   = (int*)base;                           base += 2048*4;
    unsigned short* bufxn = (unsigned short*)base;        base += (size_t)PIX*CC*2;
    unsigned short* qkvbt = (unsigned short*)base;        base += (size_t)4*768*256*2;
    unsigned short* wobt  = (unsigned short*)base;        base += (size_t)4*256*256*2;
    unsigned short* m1bt  = (unsigned short*)base;        base += (size_t)4*1024*256*2;
    unsigned short* m2bt  = (unsigned short*)base;        base += (size_t)4*256*1024*2;
    unsigned short* ssebt = (unsigned short*)base;        base += (size_t)256*256*2;
    unsigned short* cvbt  = (unsigned short*)base;        base += (size_t)9*256*256*2;

    unsigned short* attnB = (unsigned short*)buftmp;      // attn output bf16 (overlays buftmp)

    // ---- weight prep (bf16, transposed to [N,K]) ----
    wtrans<<<dim3(24, 8, 4), dim3(32,32), 0, stream>>>(qkvw, qkvbt, 256, 768);
    wtrans<<<dim3(8, 8, 4),  dim3(32,32), 0, stream>>>(wow,  wobt,  256, 256);
    wtrans<<<dim3(32, 8, 4), dim3(32,32), 0, stream>>>(mlp1w, m1bt, 256, 1024);
    wtrans<<<dim3(8, 32, 4), dim3(32,32), 0, stream>>>(mlp2w, m2bt, 1024, 256);
    tobf16<<<256, 256, 0, stream>>>(ssew, ssebt, 65536);
    convw_reorder<<<2304, 256, 0, stream>>>(convw, cvbt);

    nchw_to_nhwc<<<dim3(NB*98, 8), dim3(32,32), 0, stream>>>(x_in, bufx);

    for(int i=0;i<4;i++){
        ln_bf16<<<PIX/4,256,0,stream>>>(bufx, ln1w+i*CC, ln1b+i*CC, bufxn);
        mfma_gemm<0,false,false,true><<<dim3(6,196),256,0,stream>>>(
            bufxn, qkvbt+(size_t)i*768*256, qkvb+i*768, nullptr, nullptr, nullptr, qkvB, PIX, 768, 256);
        winmean_kernel<<<NB*P2,256,0,stream>>>(qkvB, qwin, kwin);
        route_kernel<<<NB*P2,64,0,stream>>>(qwin, kwin, idxb);
        attn_kernel<<<NB*P2*8,64,0,stream>>>(qkvB, idxb, attnB);
        lepe_kernel<<<dim3(49,4,NB),256,0,stream>>>(qkvB, attnB, lepew+(size_t)i*CC*25, lepeb+i*CC, bufxn);
        mfma_gemm<0,true,true,false><<<dim3(2,196),256,0,stream>>>(
            bufxn, wobt+(size_t)i*256*256, wob+i*CC, bufx, nullptr, bufx, nullptr, PIX, 256, 256);
        ln_bf16<<<PIX/4,256,0,stream>>>(bufx, ln2w+i*CC, ln2b+i*CC, bufxn);
        mfma_gemm<1,false,false,true><<<dim3(8,196),256,0,stream>>>(
            bufxn, m1bt+(size_t)i*1024*256, mlp1b+i*1024, nullptr, nullptr, nullptr, hid, PIX, 1024, 256);
        mfma_gemm<0,true,true,false><<<dim3(2,196),256,0,stream>>>(
            hid, m2bt+(size_t)i*256*1024, mlp2b+i*CC, bufx, nullptr, bufx, nullptr, PIX, 256, 1024);
    }

    hipMemsetAsync(pooled, 0, NB*CC*sizeof(float), stream);
    pool_kernel<<<dim3(49,NB),256,0,stream>>>(bufx, pooled);
    cse_kernel<<<NB,256,0,stream>>>(pooled, cse1w, cse1b, cse2w, cse2b, cfac);
    tobf16<<<PIX,256,0,stream>>>(bufx, bufxn, PIX*CC);
    hipMemsetAsync(Ppad, 0, (size_t)27136*256*2, stream);
    mfma_gemm<3,false,false,false><<<dim3(2,196),256,0,stream>>>(
        bufxn, ssebt, sseb, bufx, cfac, nullptr, Ppad, PIX, 256, 256);
    conv_gemm<<<dim3(2,211),256,0,stream>>>(Ppad, cvbt, convb, out);
}